// Round 3
// baseline (509.498 us; speedup 1.0000x reference)
//
#include <hip/hip_runtime.h>
#include <math.h>

#define N_NODES 50000
#define N_EDGES 800000
#define NEG 0.2f

// ---------------- CSR build ----------------

__global__ void zero_kernel(int* a, int n) {
    int i = blockIdx.x * blockDim.x + threadIdx.x;
    if (i < n) a[i] = 0;
}

__global__ void count_kernel(const int* __restrict__ dst, int* cnt, int E) {
    int i = blockIdx.x * blockDim.x + threadIdx.x;
    if (i < E) atomicAdd(&cnt[dst[i]], 1);
}

// multi-block scan: per-block exclusive scan of 256 elements + block total
__global__ void scan1_kernel(const int* __restrict__ cnt, int* rowptr, int* partials, int n) {
    __shared__ int sh[256];
    int tid = threadIdx.x;
    int i = blockIdx.x * 256 + tid;
    int v = (i < n) ? cnt[i] : 0;
    sh[tid] = v;
    __syncthreads();
    for (int off = 1; off < 256; off <<= 1) {
        int t = (tid >= off) ? sh[tid - off] : 0;
        __syncthreads();
        sh[tid] += t;
        __syncthreads();
    }
    if (i < n) rowptr[i] = sh[tid] - v;  // exclusive within block
    if (tid == 255) partials[blockIdx.x] = sh[255];
}

__global__ void scan2_kernel(int* partials, int nb) {
    __shared__ int sh[256];
    int tid = threadIdx.x;
    int v = (tid < nb) ? partials[tid] : 0;
    sh[tid] = v;
    __syncthreads();
    for (int off = 1; off < 256; off <<= 1) {
        int t = (tid >= off) ? sh[tid - off] : 0;
        __syncthreads();
        sh[tid] += t;
        __syncthreads();
    }
    if (tid < nb) partials[tid] = sh[tid] - v;  // exclusive
}

__global__ void scan3_kernel(int* rowptr, const int* __restrict__ partials, int n) {
    int i = blockIdx.x * blockDim.x + threadIdx.x;
    if (i < n) rowptr[i] += partials[i >> 8];
    if (i == 0) rowptr[n] = N_EDGES;
}

// record each edge's CSR slot (coalesced eidx write)
__global__ void fill_kernel(const int* __restrict__ dst, const int* __restrict__ rowptr,
                            int* fillc, int* eidx, int E) {
    int i = blockIdx.x * blockDim.x + threadIdx.x;
    if (i < E) {
        int d = dst[i];
        eidx[i] = rowptr[d] + atomicAdd(&fillc[d], 1);
    }
}

// ---------------- GEMM: A[rows,K] @ W[K,192] -> out[rows,192] ----------------
template <int K>
__global__ __launch_bounds__(256) void gemm_kernel(const float* __restrict__ A,
                                                   const float* __restrict__ W,
                                                   float* __restrict__ out, int rows) {
    constexpr int KT = 32;
    __shared__ float xs[KT][68];
    __shared__ float ws[KT][192];
    int tid = threadIdx.x;
    int tx = tid & 15;
    int ty = tid >> 4;
    int row0 = blockIdx.x * 64;

    float acc[4][12];
#pragma unroll
    for (int r = 0; r < 4; ++r)
#pragma unroll
        for (int c = 0; c < 12; ++c) acc[r][c] = 0.f;

    for (int kt = 0; kt < K; kt += KT) {
#pragma unroll
        for (int idx = tid; idx < 64 * KT; idx += 256) {
            int r = idx >> 5, kk = idx & 31;
            int rr = row0 + r;
            xs[kk][r] = (rr < rows) ? A[rr * K + kt + kk] : 0.f;
        }
#pragma unroll
        for (int idx = tid; idx < KT * 192; idx += 256) {
            int kk = idx / 192, c = idx - kk * 192;
            ws[kk][c] = W[(kt + kk) * 192 + c];
        }
        __syncthreads();
#pragma unroll 2
        for (int k = 0; k < KT; ++k) {
            float4 a4 = *(const float4*)&xs[k][ty * 4];
            float4 w0 = *(const float4*)&ws[k][tx * 12];
            float4 w1 = *(const float4*)&ws[k][tx * 12 + 4];
            float4 w2 = *(const float4*)&ws[k][tx * 12 + 8];
            float av[4] = {a4.x, a4.y, a4.z, a4.w};
            float wv[12] = {w0.x, w0.y, w0.z, w0.w, w1.x, w1.y, w1.z, w1.w,
                            w2.x, w2.y, w2.z, w2.w};
#pragma unroll
            for (int r = 0; r < 4; ++r)
#pragma unroll
                for (int c = 0; c < 12; ++c) acc[r][c] += av[r] * wv[c];
        }
        __syncthreads();
    }
#pragma unroll
    for (int r = 0; r < 4; ++r) {
        int rr = row0 + ty * 4 + r;
        if (rr < rows) {
            float4 o0 = {acc[r][0], acc[r][1], acc[r][2], acc[r][3]};
            float4 o1 = {acc[r][4], acc[r][5], acc[r][6], acc[r][7]};
            float4 o2 = {acc[r][8], acc[r][9], acc[r][10], acc[r][11]};
            *(float4*)&out[rr * 192 + tx * 12] = o0;
            *(float4*)&out[rr * 192 + tx * 12 + 4] = o1;
            *(float4*)&out[rr * 192 + tx * 12 + 8] = o2;
        }
    }
}

// ---------------- alpha dots + self-loop weight ----------------
// one wave per node: lanes 0..47 each own float4 of the 192-float h row
__global__ void alpha_kernel(const float* __restrict__ h, const float* __restrict__ att_src,
                             const float* __restrict__ att_dst, float* __restrict__ as4,
                             float* __restrict__ ad4, float* __restrict__ wself4, int n) {
    int wid = (int)((blockIdx.x * blockDim.x + threadIdx.x) >> 6);
    int l = threadIdx.x & 63;
    if (wid >= n) return;
    if (l < 48) {
        float4 hv = *(const float4*)(h + (size_t)wid * 192 + l * 4);
        float4 a = *(const float4*)(att_src + l * 4);
        float4 b = *(const float4*)(att_dst + l * 4);
        float s = hv.x * a.x + hv.y * a.y + hv.z * a.z + hv.w * a.w;
        float dd = hv.x * b.x + hv.y * b.y + hv.z * b.z + hv.w * b.w;
        for (int off = 1; off < 16; off <<= 1) {
            s += __shfl_xor(s, off);
            dd += __shfl_xor(dd, off);
        }
        if ((l & 15) == 0) {
            int hh = l >> 4;
            as4[wid * 4 + hh] = s;
            ad4[wid * 4 + hh] = dd;
            float v = s + dd;
            v = v > 0.f ? v : NEG * v;
            wself4[wid * 4 + hh] = __expf(v);
        }
    }
}

// ---------------- per-edge weights (no max subtraction; scores ~N(0,2)) ----------------
__global__ void weight_kernel(const int* __restrict__ src, const int* __restrict__ dst,
                              const int* __restrict__ eidx, const float* __restrict__ as4,
                              const float* __restrict__ ad4, float4* __restrict__ ew, int E) {
    int i = blockIdx.x * blockDim.x + threadIdx.x;
    if (i >= E) return;
    int s = src[i], d = dst[i], pos = eidx[i];
    float4 a = *(const float4*)(as4 + s * 4);
    float4 b = *(const float4*)(ad4 + d * 4);
    float v0 = a.x + b.x; v0 = v0 > 0.f ? v0 : NEG * v0;
    float v1 = a.y + b.y; v1 = v1 > 0.f ? v1 : NEG * v1;
    float v2 = a.z + b.z; v2 = v2 > 0.f ? v2 : NEG * v2;
    float4 r;
    r.x = __int_as_float(s);
    r.y = __expf(v0);
    r.z = __expf(v1);
    r.w = __expf(v2);
    ew[pos] = r;
}

// ---------------- aggregation: one wave per node, 48 active lanes ----------------
// lane l (0..47): head hl=l>>4, channels (l&15)*4 .. +3 of that head
template <bool RELU>
__global__ __launch_bounds__(256) void aggregate_kernel(const float* __restrict__ h,
                                                        const float4* __restrict__ ew,
                                                        const float* __restrict__ wself4,
                                                        const float* __restrict__ bias,
                                                        const int* __restrict__ rowptr,
                                                        float* __restrict__ out, int n) {
    __shared__ float sh[4][192];
    int wid = (int)((blockIdx.x * blockDim.x + threadIdx.x) >> 6);
    int l = threadIdx.x & 63;
    int wv = threadIdx.x >> 6;
    bool valid = wid < n;
    int d = valid ? wid : 0;
    if (valid && l < 48) {
        int hl = l >> 4;
        int r0 = rowptr[d], r1 = rowptr[d + 1];
        float4 wsf = *(const float4*)(wself4 + d * 4);
        float w = hl == 0 ? wsf.x : (hl == 1 ? wsf.y : wsf.z);
        float4 hv = *(const float4*)(h + (size_t)d * 192 + l * 4);
        float ax = w * hv.x, ay = w * hv.y, az = w * hv.z, aw = w * hv.w;
        float den = w;
        for (int j = r0; j < r1; ++j) {
            float4 e = ew[j];  // wave-uniform address -> scalar load
            int s = __float_as_int(e.x);
            float we = hl == 0 ? e.y : (hl == 1 ? e.z : e.w);
            float4 hv2 = *(const float4*)(h + (size_t)s * 192 + l * 4);
            ax += we * hv2.x;
            ay += we * hv2.y;
            az += we * hv2.z;
            aw += we * hv2.w;
            den += we;
        }
        float r = 1.f / den;
        float4 o = {ax * r, ay * r, az * r, aw * r};
        *(float4*)&sh[wv][l * 4] = o;
    }
    __syncthreads();
    if (valid) {
        float o = (sh[wv][l] + sh[wv][64 + l] + sh[wv][128 + l]) * (1.f / 3.f) + bias[l];
        if (RELU) o = fmaxf(o, 0.f);
        out[(size_t)d * 64 + l] = o;
    }
}

extern "C" void kernel_launch(void* const* d_in, const int* in_sizes, int n_in,
                              void* d_out, int out_size, void* d_ws, size_t ws_size,
                              hipStream_t stream) {
    const float* x = (const float*)d_in[0];       // [N,128]
    const int* ei = (const int*)d_in[1];          // [2,E]
    const float* W1 = (const float*)d_in[2];      // [128,192]
    const float* att_s1 = (const float*)d_in[3];  // [3,64]
    const float* att_d1 = (const float*)d_in[4];
    const float* b1 = (const float*)d_in[5];      // [64]
    const float* W2 = (const float*)d_in[6];      // [64,192]
    const float* att_s2 = (const float*)d_in[7];
    const float* att_d2 = (const float*)d_in[8];
    const float* b2 = (const float*)d_in[9];
    const int* src = ei;
    const int* dst = ei + N_EDGES;

    // workspace layout (all float4-aligned)
    float* h = (float*)d_ws;                    // N*192
    float* ewf = h + (size_t)N_NODES * 192;     // E*4
    float* as4 = ewf + (size_t)N_EDGES * 4;     // N*4
    float* ad4 = as4 + N_NODES * 4;             // N*4
    float* wself4 = ad4 + N_NODES * 4;          // N*4
    int* cnt = (int*)(wself4 + N_NODES * 4);    // N
    int* fillc = cnt + N_NODES;                 // N
    int* rowptr = fillc + N_NODES;              // N+1
    int* eidx = rowptr + N_NODES + 1;           // E
    int* partials = (int*)ewf;                  // reuse (ew written later)
    float4* ew = (float4*)ewf;

    float* outf = (float*)d_out;                // doubles as layer-1 output [N,64]
    const int NB = (N_NODES + 255) / 256;

    // CSR build (shared by both layers)
    zero_kernel<<<(2 * N_NODES + 255) / 256, 256, 0, stream>>>(cnt, 2 * N_NODES);
    count_kernel<<<(N_EDGES + 255) / 256, 256, 0, stream>>>(dst, cnt, N_EDGES);
    scan1_kernel<<<NB, 256, 0, stream>>>(cnt, rowptr, partials, N_NODES);
    scan2_kernel<<<1, 256, 0, stream>>>(partials, NB);
    scan3_kernel<<<NB, 256, 0, stream>>>(rowptr, partials, N_NODES);
    fill_kernel<<<(N_EDGES + 255) / 256, 256, 0, stream>>>(dst, rowptr, fillc, eidx, N_EDGES);

    // layer 1
    gemm_kernel<128><<<(N_NODES + 63) / 64, 256, 0, stream>>>(x, W1, h, N_NODES);
    alpha_kernel<<<(N_NODES + 3) / 4, 256, 0, stream>>>(h, att_s1, att_d1, as4, ad4, wself4, N_NODES);
    weight_kernel<<<(N_EDGES + 255) / 256, 256, 0, stream>>>(src, dst, eidx, as4, ad4, ew, N_EDGES);
    aggregate_kernel<true><<<(N_NODES + 3) / 4, 256, 0, stream>>>(h, ew, wself4, b1, rowptr, outf, N_NODES);

    // layer 2 (reads layer-1 output from d_out, then overwrites d_out)
    gemm_kernel<64><<<(N_NODES + 63) / 64, 256, 0, stream>>>(outf, W2, h, N_NODES);
    alpha_kernel<<<(N_NODES + 3) / 4, 256, 0, stream>>>(h, att_s2, att_d2, as4, ad4, wself4, N_NODES);
    weight_kernel<<<(N_EDGES + 255) / 256, 256, 0, stream>>>(src, dst, eidx, as4, ad4, ew, N_EDGES);
    aggregate_kernel<false><<<(N_NODES + 3) / 4, 256, 0, stream>>>(h, ew, wself4, b2, rowptr, outf, N_NODES);
}

// Round 4
// 460.966 us; speedup vs baseline: 1.1053x; 1.1053x over previous
//
#include <hip/hip_runtime.h>
#include <math.h>

#define N_NODES 50000
#define N_EDGES 800000
#define NEG 0.2f

// ---------------- CSR build ----------------

__global__ void zero_kernel(int* a, int n) {
    int i = blockIdx.x * blockDim.x + threadIdx.x;
    if (i < n) a[i] = 0;
}

__global__ void count_kernel(const int* __restrict__ dst, int* cnt, int E) {
    int i = blockIdx.x * blockDim.x + threadIdx.x;
    if (i < E) atomicAdd(&cnt[dst[i]], 1);
}

// multi-block scan: per-block exclusive scan of 256 elements + block total
__global__ void scan1_kernel(const int* __restrict__ cnt, int* rowptr, int* partials, int n) {
    __shared__ int sh[256];
    int tid = threadIdx.x;
    int i = blockIdx.x * 256 + tid;
    int v = (i < n) ? cnt[i] : 0;
    sh[tid] = v;
    __syncthreads();
    for (int off = 1; off < 256; off <<= 1) {
        int t = (tid >= off) ? sh[tid - off] : 0;
        __syncthreads();
        sh[tid] += t;
        __syncthreads();
    }
    if (i < n) rowptr[i] = sh[tid] - v;  // exclusive within block
    if (tid == 255) partials[blockIdx.x] = sh[255];
}

__global__ void scan2_kernel(int* partials, int nb) {
    __shared__ int sh[256];
    int tid = threadIdx.x;
    int v = (tid < nb) ? partials[tid] : 0;
    sh[tid] = v;
    __syncthreads();
    for (int off = 1; off < 256; off <<= 1) {
        int t = (tid >= off) ? sh[tid - off] : 0;
        __syncthreads();
        sh[tid] += t;
        __syncthreads();
    }
    if (tid < nb) partials[tid] = sh[tid] - v;  // exclusive
}

__global__ void scan3_kernel(int* rowptr, const int* __restrict__ partials, int n) {
    int i = blockIdx.x * blockDim.x + threadIdx.x;
    if (i < n) rowptr[i] += partials[i >> 8];
    if (i == 0) rowptr[n] = N_EDGES;
}

__global__ void fill_kernel(const int* __restrict__ src, const int* __restrict__ dst,
                            const int* __restrict__ rowptr, int* fillc, int* col, int E) {
    int i = blockIdx.x * blockDim.x + threadIdx.x;
    if (i < E) {
        int d = dst[i];
        int pos = rowptr[d] + atomicAdd(&fillc[d], 1);
        col[pos] = src[i];
    }
}

// ---------------- GEMM: A[rows,K] @ W[K,192] -> out[rows,192] ----------------
template <int K>
__global__ __launch_bounds__(256) void gemm_kernel(const float* __restrict__ A,
                                                   const float* __restrict__ W,
                                                   float* __restrict__ out, int rows) {
    constexpr int KT = 32;
    __shared__ float xs[KT][68];
    __shared__ float ws[KT][192];
    int tid = threadIdx.x;
    int tx = tid & 15;
    int ty = tid >> 4;
    int row0 = blockIdx.x * 64;

    float acc[4][12];
#pragma unroll
    for (int r = 0; r < 4; ++r)
#pragma unroll
        for (int c = 0; c < 12; ++c) acc[r][c] = 0.f;

    for (int kt = 0; kt < K; kt += KT) {
#pragma unroll
        for (int idx = tid; idx < 64 * KT; idx += 256) {
            int r = idx >> 5, kk = idx & 31;
            int rr = row0 + r;
            xs[kk][r] = (rr < rows) ? A[rr * K + kt + kk] : 0.f;
        }
#pragma unroll
        for (int idx = tid; idx < KT * 192; idx += 256) {
            int kk = idx / 192, c = idx - kk * 192;
            ws[kk][c] = W[(kt + kk) * 192 + c];
        }
        __syncthreads();
#pragma unroll 2
        for (int k = 0; k < KT; ++k) {
            float4 a4 = *(const float4*)&xs[k][ty * 4];
            float4 w0 = *(const float4*)&ws[k][tx * 12];
            float4 w1 = *(const float4*)&ws[k][tx * 12 + 4];
            float4 w2 = *(const float4*)&ws[k][tx * 12 + 8];
            float av[4] = {a4.x, a4.y, a4.z, a4.w};
            float wv[12] = {w0.x, w0.y, w0.z, w0.w, w1.x, w1.y, w1.z, w1.w,
                            w2.x, w2.y, w2.z, w2.w};
#pragma unroll
            for (int r = 0; r < 4; ++r)
#pragma unroll
                for (int c = 0; c < 12; ++c) acc[r][c] += av[r] * wv[c];
        }
        __syncthreads();
    }
#pragma unroll
    for (int r = 0; r < 4; ++r) {
        int rr = row0 + ty * 4 + r;
        if (rr < rows) {
            float4 o0 = {acc[r][0], acc[r][1], acc[r][2], acc[r][3]};
            float4 o1 = {acc[r][4], acc[r][5], acc[r][6], acc[r][7]};
            float4 o2 = {acc[r][8], acc[r][9], acc[r][10], acc[r][11]};
            *(float4*)&out[rr * 192 + tx * 12] = o0;
            *(float4*)&out[rr * 192 + tx * 12 + 4] = o1;
            *(float4*)&out[rr * 192 + tx * 12 + 8] = o2;
        }
    }
}

// ---------------- alpha dots + self-loop weight ----------------
// one wave per node: lanes 0..47 each own a float4 of the 192-float h row
__global__ void alpha_kernel(const float* __restrict__ h, const float* __restrict__ att_src,
                             const float* __restrict__ att_dst, float* __restrict__ as4,
                             float* __restrict__ ad4, float* __restrict__ wself4, int n) {
    int wid = (int)((blockIdx.x * blockDim.x + threadIdx.x) >> 6);
    int l = threadIdx.x & 63;
    if (wid >= n) return;
    if (l < 48) {
        float4 hv = *(const float4*)(h + (size_t)wid * 192 + l * 4);
        float4 a = *(const float4*)(att_src + l * 4);
        float4 b = *(const float4*)(att_dst + l * 4);
        float s = hv.x * a.x + hv.y * a.y + hv.z * a.z + hv.w * a.w;
        float dd = hv.x * b.x + hv.y * b.y + hv.z * b.z + hv.w * b.w;
        for (int off = 1; off < 16; off <<= 1) {
            s += __shfl_xor(s, off);
            dd += __shfl_xor(dd, off);
        }
        if ((l & 15) == 0) {
            int hh = l >> 4;
            as4[wid * 4 + hh] = s;
            ad4[wid * 4 + hh] = dd;
            float v = s + dd;
            v = v > 0.f ? v : NEG * v;
            wself4[wid * 4 + hh] = __expf(v);
        }
    }
}

// ---------------- aggregation: one wave per node, fused weights, 8-deep MLP ----------------
// lane l (0..47): head hl=l>>4, channels (l&15)*4 .. +3 of that head
template <bool RELU>
__global__ __launch_bounds__(256) void aggregate_kernel(const float* __restrict__ h,
                                                        const float* __restrict__ as_,
                                                        const float* __restrict__ ad4,
                                                        const float* __restrict__ wself4,
                                                        const float* __restrict__ bias,
                                                        const int* __restrict__ rowptr,
                                                        const int* __restrict__ col,
                                                        float* __restrict__ out, int n) {
    constexpr int U = 8;
    __shared__ float sh[4][192];
    int wid = (int)((blockIdx.x * blockDim.x + threadIdx.x) >> 6);
    int l = threadIdx.x & 63;
    int wv = threadIdx.x >> 6;
    bool valid = wid < n;
    int d = valid ? wid : 0;
    if (valid && l < 48) {
        int hl = l >> 4;
        int r0 = rowptr[d], r1 = rowptr[d + 1];
        float adh = ad4[d * 4 + hl];
        float w = wself4[d * 4 + hl];
        float4 hv = *(const float4*)(h + (size_t)d * 192 + l * 4);
        float ax = w * hv.x, ay = w * hv.y, az = w * hv.z, aw = w * hv.w;
        float den = w;

        int j = r0;
        for (; j + U <= r1; j += U) {
            int s[U];
            float av[U];
            float4 g[U];
#pragma unroll
            for (int u = 0; u < U; ++u) s[u] = col[j + u];
#pragma unroll
            for (int u = 0; u < U; ++u) av[u] = as_[s[u] * 4 + hl];
#pragma unroll
            for (int u = 0; u < U; ++u)
                g[u] = *(const float4*)(h + (size_t)s[u] * 192 + l * 4);
#pragma unroll
            for (int u = 0; u < U; ++u) {
                float v = av[u] + adh;
                v = v > 0.f ? v : NEG * v;
                float we = __expf(v);
                den += we;
                ax += we * g[u].x;
                ay += we * g[u].y;
                az += we * g[u].z;
                aw += we * g[u].w;
            }
        }
        for (; j < r1; ++j) {
            int s = col[j];
            float v = as_[s * 4 + hl] + adh;
            v = v > 0.f ? v : NEG * v;
            float we = __expf(v);
            float4 g = *(const float4*)(h + (size_t)s * 192 + l * 4);
            den += we;
            ax += we * g.x;
            ay += we * g.y;
            az += we * g.z;
            aw += we * g.w;
        }
        float r = 1.f / den;
        float4 o = {ax * r, ay * r, az * r, aw * r};
        *(float4*)&sh[wv][l * 4] = o;
    }
    __syncthreads();
    if (valid) {
        float o = (sh[wv][l] + sh[wv][64 + l] + sh[wv][128 + l]) * (1.f / 3.f) + bias[l];
        if (RELU) o = fmaxf(o, 0.f);
        out[(size_t)d * 64 + l] = o;
    }
}

extern "C" void kernel_launch(void* const* d_in, const int* in_sizes, int n_in,
                              void* d_out, int out_size, void* d_ws, size_t ws_size,
                              hipStream_t stream) {
    const float* x = (const float*)d_in[0];       // [N,128]
    const int* ei = (const int*)d_in[1];          // [2,E]
    const float* W1 = (const float*)d_in[2];      // [128,192]
    const float* att_s1 = (const float*)d_in[3];  // [3,64]
    const float* att_d1 = (const float*)d_in[4];
    const float* b1 = (const float*)d_in[5];      // [64]
    const float* W2 = (const float*)d_in[6];      // [64,192]
    const float* att_s2 = (const float*)d_in[7];
    const float* att_d2 = (const float*)d_in[8];
    const float* b2 = (const float*)d_in[9];
    const int* src = ei;
    const int* dst = ei + N_EDGES;

    // workspace layout (all float4-aligned)
    float* h = (float*)d_ws;                    // N*192
    float* as4 = h + (size_t)N_NODES * 192;     // N*4
    float* ad4 = as4 + N_NODES * 4;             // N*4
    float* wself4 = ad4 + N_NODES * 4;          // N*4
    int* cnt = (int*)(wself4 + N_NODES * 4);    // N
    int* fillc = cnt + N_NODES;                 // N
    int* rowptr = fillc + N_NODES;              // N+1
    int* col = rowptr + N_NODES + 1;            // E
    int* partials = col + N_EDGES;              // scan partials (<=256)

    float* outf = (float*)d_out;                // doubles as layer-1 output [N,64]
    const int NB = (N_NODES + 255) / 256;

    // CSR build (shared by both layers)
    zero_kernel<<<(2 * N_NODES + 255) / 256, 256, 0, stream>>>(cnt, 2 * N_NODES);
    count_kernel<<<(N_EDGES + 255) / 256, 256, 0, stream>>>(dst, cnt, N_EDGES);
    scan1_kernel<<<NB, 256, 0, stream>>>(cnt, rowptr, partials, N_NODES);
    scan2_kernel<<<1, 256, 0, stream>>>(partials, NB);
    scan3_kernel<<<NB, 256, 0, stream>>>(rowptr, partials, N_NODES);
    fill_kernel<<<(N_EDGES + 255) / 256, 256, 0, stream>>>(src, dst, rowptr, fillc, col, N_EDGES);

    // layer 1
    gemm_kernel<128><<<(N_NODES + 63) / 64, 256, 0, stream>>>(x, W1, h, N_NODES);
    alpha_kernel<<<(N_NODES + 3) / 4, 256, 0, stream>>>(h, att_s1, att_d1, as4, ad4, wself4, N_NODES);
    aggregate_kernel<true><<<(N_NODES + 3) / 4, 256, 0, stream>>>(h, as4, ad4, wself4, b1, rowptr, col, outf, N_NODES);

    // layer 2 (reads layer-1 output from d_out, then overwrites d_out)
    gemm_kernel<64><<<(N_NODES + 63) / 64, 256, 0, stream>>>(outf, W2, h, N_NODES);
    alpha_kernel<<<(N_NODES + 3) / 4, 256, 0, stream>>>(h, att_s2, att_d2, as4, ad4, wself4, N_NODES);
    aggregate_kernel<false><<<(N_NODES + 3) / 4, 256, 0, stream>>>(h, as4, ad4, wself4, b2, rowptr, col, outf, N_NODES);
}

// Round 5
// 383.181 us; speedup vs baseline: 1.3297x; 1.2030x over previous
//
#include <hip/hip_runtime.h>
#include <hip/hip_fp16.h>
#include <math.h>

#define N_NODES 50000
#define N_EDGES 800000
#define NEG 0.2f

// ---------------- CSR build ----------------

__global__ void zero_kernel(int* a, int n) {
    int i = blockIdx.x * blockDim.x + threadIdx.x;
    if (i < n) a[i] = 0;
}

__global__ void count_kernel(const int* __restrict__ dst, int* cnt, int E) {
    int i = blockIdx.x * blockDim.x + threadIdx.x;
    if (i < E) atomicAdd(&cnt[dst[i]], 1);
}

// multi-block scan: per-block exclusive scan of 256 elements + block total
__global__ void scan1_kernel(const int* __restrict__ cnt, int* rowptr, int* partials, int n) {
    __shared__ int sh[256];
    int tid = threadIdx.x;
    int i = blockIdx.x * 256 + tid;
    int v = (i < n) ? cnt[i] : 0;
    sh[tid] = v;
    __syncthreads();
    for (int off = 1; off < 256; off <<= 1) {
        int t = (tid >= off) ? sh[tid - off] : 0;
        __syncthreads();
        sh[tid] += t;
        __syncthreads();
    }
    if (i < n) rowptr[i] = sh[tid] - v;  // exclusive within block
    if (tid == 255) partials[blockIdx.x] = sh[255];
}

__global__ void scan2_kernel(int* partials, int nb) {
    __shared__ int sh[256];
    int tid = threadIdx.x;
    int v = (tid < nb) ? partials[tid] : 0;
    sh[tid] = v;
    __syncthreads();
    for (int off = 1; off < 256; off <<= 1) {
        int t = (tid >= off) ? sh[tid - off] : 0;
        __syncthreads();
        sh[tid] += t;
        __syncthreads();
    }
    if (tid < nb) partials[tid] = sh[tid] - v;  // exclusive
}

__global__ void scan3_kernel(int* rowptr, const int* __restrict__ partials, int n) {
    int i = blockIdx.x * blockDim.x + threadIdx.x;
    if (i < n) rowptr[i] += partials[i >> 8];
    if (i == 0) rowptr[n] = N_EDGES;
}

// fill CSR; reuse cnt (still holds counts) via atomicSub -> no fillc array
__global__ void fill_kernel(const int* __restrict__ src, const int* __restrict__ dst,
                            const int* __restrict__ rowptr, int* cnt, int* col, int E) {
    int i = blockIdx.x * blockDim.x + threadIdx.x;
    if (i < E) {
        int d = dst[i];
        int pos = rowptr[d] + atomicSub(&cnt[d], 1) - 1;
        col[pos] = src[i];
    }
}

// ---------------- GEMM: A[rows,K] @ W[K,192] -> h16[rows,192] (fp16 out) ----------------
template <int K>
__global__ __launch_bounds__(256) void gemm_kernel(const float* __restrict__ A,
                                                   const float* __restrict__ W,
                                                   __half* __restrict__ out, int rows) {
    constexpr int KT = 32;
    __shared__ float xs[KT][68];
    __shared__ float ws[KT][192];
    int tid = threadIdx.x;
    int tx = tid & 15;
    int ty = tid >> 4;
    int row0 = blockIdx.x * 64;

    float acc[4][12];
#pragma unroll
    for (int r = 0; r < 4; ++r)
#pragma unroll
        for (int c = 0; c < 12; ++c) acc[r][c] = 0.f;

    for (int kt = 0; kt < K; kt += KT) {
#pragma unroll
        for (int idx = tid; idx < 64 * KT; idx += 256) {
            int r = idx >> 5, kk = idx & 31;
            int rr = row0 + r;
            xs[kk][r] = (rr < rows) ? A[rr * K + kt + kk] : 0.f;
        }
#pragma unroll
        for (int idx = tid; idx < KT * 192; idx += 256) {
            int kk = idx / 192, c = idx - kk * 192;
            ws[kk][c] = W[(kt + kk) * 192 + c];
        }
        __syncthreads();
#pragma unroll 2
        for (int k = 0; k < KT; ++k) {
            float4 a4 = *(const float4*)&xs[k][ty * 4];
            float4 w0 = *(const float4*)&ws[k][tx * 12];
            float4 w1 = *(const float4*)&ws[k][tx * 12 + 4];
            float4 w2 = *(const float4*)&ws[k][tx * 12 + 8];
            float av[4] = {a4.x, a4.y, a4.z, a4.w};
            float wv[12] = {w0.x, w0.y, w0.z, w0.w, w1.x, w1.y, w1.z, w1.w,
                            w2.x, w2.y, w2.z, w2.w};
#pragma unroll
            for (int r = 0; r < 4; ++r)
#pragma unroll
                for (int c = 0; c < 12; ++c) acc[r][c] += av[r] * wv[c];
        }
        __syncthreads();
    }
#pragma unroll
    for (int r = 0; r < 4; ++r) {
        int rr = row0 + ty * 4 + r;
        if (rr < rows) {
            __half2* o = (__half2*)(out + (size_t)rr * 192 + tx * 12);
#pragma unroll
            for (int c = 0; c < 6; ++c)
                o[c] = __floats2half2_rn(acc[r][2 * c], acc[r][2 * c + 1]);
        }
    }
}

// ---------------- alpha dots + self-loop weight (h16 input) ----------------
// one wave per node: lanes 0..47 each own 4 halves of the 192-half row
__global__ void alpha_kernel(const __half* __restrict__ h, const float* __restrict__ att_src,
                             const float* __restrict__ att_dst, float* __restrict__ as4,
                             float* __restrict__ ad4, float* __restrict__ wself4, int n) {
    int wid = (int)((blockIdx.x * blockDim.x + threadIdx.x) >> 6);
    int l = threadIdx.x & 63;
    if (wid >= n) return;
    if (l < 48) {
        float2 raw = *(const float2*)(h + (size_t)wid * 192 + l * 4);
        float2 h01 = __half22float2(*(__half2*)&raw.x);
        float2 h23 = __half22float2(*(__half2*)&raw.y);
        float4 a = *(const float4*)(att_src + l * 4);
        float4 b = *(const float4*)(att_dst + l * 4);
        float s = h01.x * a.x + h01.y * a.y + h23.x * a.z + h23.y * a.w;
        float dd = h01.x * b.x + h01.y * b.y + h23.x * b.z + h23.y * b.w;
        for (int off = 1; off < 16; off <<= 1) {
            s += __shfl_xor(s, off);
            dd += __shfl_xor(dd, off);
        }
        if ((l & 15) == 0) {
            int hh = l >> 4;
            as4[wid * 4 + hh] = s;
            ad4[wid * 4 + hh] = dd;
            float v = s + dd;
            v = v > 0.f ? v : NEG * v;
            wself4[wid * 4 + hh] = __expf(v);
        }
    }
}

// ---------------- aggregation: one wave per node, fp16 gathers, U-deep MLP ----------------
// lane l (0..47): head hl=l>>4, channels (l&15)*4 .. +3 of that head
template <bool RELU>
__global__ __launch_bounds__(256) void aggregate_kernel(const __half* __restrict__ h,
                                                        const float* __restrict__ as_,
                                                        const float* __restrict__ ad4,
                                                        const float* __restrict__ wself4,
                                                        const float* __restrict__ bias,
                                                        const int* __restrict__ rowptr,
                                                        const int* __restrict__ col,
                                                        float* __restrict__ out, int n) {
    constexpr int U = 8;
    __shared__ float sh[4][192];
    int wid = (int)((blockIdx.x * blockDim.x + threadIdx.x) >> 6);
    int l = threadIdx.x & 63;
    int wv = threadIdx.x >> 6;
    bool valid = wid < n;
    int d = valid ? wid : 0;
    if (valid && l < 48) {
        int hl = l >> 4;
        int r0 = rowptr[d], r1 = rowptr[d + 1];
        float adh = ad4[d * 4 + hl];
        float w = wself4[d * 4 + hl];
        float2 sraw = *(const float2*)(h + (size_t)d * 192 + l * 4);
        float2 s01 = __half22float2(*(__half2*)&sraw.x);
        float2 s23 = __half22float2(*(__half2*)&sraw.y);
        float ax = w * s01.x, ay = w * s01.y, az = w * s23.x, aw = w * s23.y;
        float den = w;

        int j = r0;
        for (; j + U <= r1; j += U) {
            int s[U];
            float av[U];
            float2 g[U];
#pragma unroll
            for (int u = 0; u < U; ++u) s[u] = col[j + u];
#pragma unroll
            for (int u = 0; u < U; ++u) av[u] = as_[s[u] * 4 + hl];
#pragma unroll
            for (int u = 0; u < U; ++u)
                g[u] = *(const float2*)(h + (size_t)s[u] * 192 + l * 4);
#pragma unroll
            for (int u = 0; u < U; ++u) {
                float v = av[u] + adh;
                v = v > 0.f ? v : NEG * v;
                float we = __expf(v);
                float2 g01 = __half22float2(*(__half2*)&g[u].x);
                float2 g23 = __half22float2(*(__half2*)&g[u].y);
                den += we;
                ax += we * g01.x;
                ay += we * g01.y;
                az += we * g23.x;
                aw += we * g23.y;
            }
        }
        for (; j < r1; ++j) {
            int s = col[j];
            float v = as_[s * 4 + hl] + adh;
            v = v > 0.f ? v : NEG * v;
            float we = __expf(v);
            float2 g = *(const float2*)(h + (size_t)s * 192 + l * 4);
            float2 g01 = __half22float2(*(__half2*)&g.x);
            float2 g23 = __half22float2(*(__half2*)&g.y);
            den += we;
            ax += we * g01.x;
            ay += we * g01.y;
            az += we * g23.x;
            aw += we * g23.y;
        }
        float r = 1.f / den;
        float4 o = {ax * r, ay * r, az * r, aw * r};
        *(float4*)&sh[wv][l * 4] = o;
    }
    __syncthreads();
    if (valid) {
        float o = (sh[wv][l] + sh[wv][64 + l] + sh[wv][128 + l]) * (1.f / 3.f) + bias[l];
        if (RELU) o = fmaxf(o, 0.f);
        out[(size_t)d * 64 + l] = o;
    }
}

extern "C" void kernel_launch(void* const* d_in, const int* in_sizes, int n_in,
                              void* d_out, int out_size, void* d_ws, size_t ws_size,
                              hipStream_t stream) {
    const float* x = (const float*)d_in[0];       // [N,128]
    const int* ei = (const int*)d_in[1];          // [2,E]
    const float* W1 = (const float*)d_in[2];      // [128,192]
    const float* att_s1 = (const float*)d_in[3];  // [3,64]
    const float* att_d1 = (const float*)d_in[4];
    const float* b1 = (const float*)d_in[5];      // [64]
    const float* W2 = (const float*)d_in[6];      // [64,192]
    const float* att_s2 = (const float*)d_in[7];
    const float* att_d2 = (const float*)d_in[8];
    const float* b2 = (const float*)d_in[9];
    const int* src = ei;
    const int* dst = ei + N_EDGES;

    // workspace layout (16B-aligned blocks)
    __half* h16 = (__half*)d_ws;                      // N*192 halves
    float* as4 = (float*)(h16 + (size_t)N_NODES * 192);  // N*4
    float* ad4 = as4 + N_NODES * 4;                   // N*4
    float* wself4 = ad4 + N_NODES * 4;                // N*4
    int* cnt = (int*)(wself4 + N_NODES * 4);          // N
    int* rowptr = cnt + N_NODES;                      // N+1
    int* col = rowptr + N_NODES + 1;                  // E
    int* partials = col + N_EDGES;                    // <=256

    float* outf = (float*)d_out;                      // doubles as layer-1 output [N,64]
    const int NB = (N_NODES + 255) / 256;

    // CSR build (shared by both layers)
    zero_kernel<<<(N_NODES + 255) / 256, 256, 0, stream>>>(cnt, N_NODES);
    count_kernel<<<(N_EDGES + 255) / 256, 256, 0, stream>>>(dst, cnt, N_EDGES);
    scan1_kernel<<<NB, 256, 0, stream>>>(cnt, rowptr, partials, N_NODES);
    scan2_kernel<<<1, 256, 0, stream>>>(partials, NB);
    scan3_kernel<<<NB, 256, 0, stream>>>(rowptr, partials, N_NODES);
    fill_kernel<<<(N_EDGES + 255) / 256, 256, 0, stream>>>(src, dst, rowptr, cnt, col, N_EDGES);

    // layer 1
    gemm_kernel<128><<<(N_NODES + 63) / 64, 256, 0, stream>>>(x, W1, h16, N_NODES);
    alpha_kernel<<<(N_NODES + 3) / 4, 256, 0, stream>>>(h16, att_s1, att_d1, as4, ad4, wself4, N_NODES);
    aggregate_kernel<true><<<(N_NODES + 3) / 4, 256, 0, stream>>>(h16, as4, ad4, wself4, b1, rowptr, col, outf, N_NODES);

    // layer 2 (reads layer-1 output from d_out, then overwrites d_out)
    gemm_kernel<64><<<(N_NODES + 63) / 64, 256, 0, stream>>>(outf, W2, h16, N_NODES);
    alpha_kernel<<<(N_NODES + 3) / 4, 256, 0, stream>>>(h16, att_s2, att_d2, as4, ad4, wself4, N_NODES);
    aggregate_kernel<false><<<(N_NODES + 3) / 4, 256, 0, stream>>>(h16, as4, ad4, wself4, b2, rowptr, col, outf, N_NODES);
}

// Round 6
// 364.173 us; speedup vs baseline: 1.3991x; 1.0522x over previous
//
#include <hip/hip_runtime.h>
#include <hip/hip_fp16.h>
#include <math.h>

#define N_NODES 50000
#define N_EDGES 800000
#define NEG 0.2f

// ---------------- CSR build ----------------

__global__ void zero_kernel(int* a, int n) {
    int i = blockIdx.x * blockDim.x + threadIdx.x;
    if (i < n) a[i] = 0;
}

__global__ void count_kernel(const int* __restrict__ dst, int* cnt, int E) {
    int i = blockIdx.x * blockDim.x + threadIdx.x;
    if (i < E) atomicAdd(&cnt[dst[i]], 1);
}

// multi-block scan: per-block exclusive scan of 256 elements + block total
__global__ void scan1_kernel(const int* __restrict__ cnt, int* rowptr, int* partials, int n) {
    __shared__ int sh[256];
    int tid = threadIdx.x;
    int i = blockIdx.x * 256 + tid;
    int v = (i < n) ? cnt[i] : 0;
    sh[tid] = v;
    __syncthreads();
    for (int off = 1; off < 256; off <<= 1) {
        int t = (tid >= off) ? sh[tid - off] : 0;
        __syncthreads();
        sh[tid] += t;
        __syncthreads();
    }
    if (i < n) rowptr[i] = sh[tid] - v;  // exclusive within block
    if (tid == 255) partials[blockIdx.x] = sh[255];
}

__global__ void scan2_kernel(int* partials, int nb) {
    __shared__ int sh[256];
    int tid = threadIdx.x;
    int v = (tid < nb) ? partials[tid] : 0;
    sh[tid] = v;
    __syncthreads();
    for (int off = 1; off < 256; off <<= 1) {
        int t = (tid >= off) ? sh[tid - off] : 0;
        __syncthreads();
        sh[tid] += t;
        __syncthreads();
    }
    if (tid < nb) partials[tid] = sh[tid] - v;  // exclusive
}

__global__ void scan3_kernel(int* rowptr, const int* __restrict__ partials, int n) {
    int i = blockIdx.x * blockDim.x + threadIdx.x;
    if (i < n) rowptr[i] += partials[i >> 8];
    if (i == 0) rowptr[n] = N_EDGES;
}

// fill CSR; reuse cnt (still holds counts) via atomicSub -> no fillc array
__global__ void fill_kernel(const int* __restrict__ src, const int* __restrict__ dst,
                            const int* __restrict__ rowptr, int* cnt, int* col, int E) {
    int i = blockIdx.x * blockDim.x + threadIdx.x;
    if (i < E) {
        int d = dst[i];
        int pos = rowptr[d] + atomicSub(&cnt[d], 1) - 1;
        col[pos] = src[i];
    }
}

// ---------------- GEMM: A[rows,K] @ W[K,192] -> h16[rows,192] (fp16 out)
// fused epilogue: as4/ad4/wself4 (att dots + self-loop weight) per row.
// thread (ty,tx): rows ty*4..+3, cols tx*12..+11; row's 16 threads = contiguous lanes.
template <int K>
__global__ __launch_bounds__(256) void gemm_kernel(const float* __restrict__ A,
                                                   const float* __restrict__ W,
                                                   __half* __restrict__ out,
                                                   const float* __restrict__ att_src,
                                                   const float* __restrict__ att_dst,
                                                   float* __restrict__ as4,
                                                   float* __restrict__ ad4,
                                                   float* __restrict__ wself4, int rows) {
    constexpr int KT = 32;
    __shared__ float xs[KT][68];
    __shared__ float ws[KT][192];
    int tid = threadIdx.x;
    int tx = tid & 15;
    int ty = tid >> 4;
    int row0 = blockIdx.x * 64;

    float acc[4][12];
#pragma unroll
    for (int r = 0; r < 4; ++r)
#pragma unroll
        for (int c = 0; c < 12; ++c) acc[r][c] = 0.f;

    for (int kt = 0; kt < K; kt += KT) {
#pragma unroll
        for (int idx = tid; idx < 64 * KT; idx += 256) {
            int r = idx >> 5, kk = idx & 31;
            int rr = row0 + r;
            xs[kk][r] = (rr < rows) ? A[rr * K + kt + kk] : 0.f;
        }
#pragma unroll
        for (int idx = tid; idx < KT * 192; idx += 256) {
            int kk = idx / 192, c = idx - kk * 192;
            ws[kk][c] = W[(kt + kk) * 192 + c];
        }
        __syncthreads();
#pragma unroll 2
        for (int k = 0; k < KT; ++k) {
            float4 a4 = *(const float4*)&xs[k][ty * 4];
            float4 w0 = *(const float4*)&ws[k][tx * 12];
            float4 w1 = *(const float4*)&ws[k][tx * 12 + 4];
            float4 w2 = *(const float4*)&ws[k][tx * 12 + 8];
            float av[4] = {a4.x, a4.y, a4.z, a4.w};
            float wv[12] = {w0.x, w0.y, w0.z, w0.w, w1.x, w1.y, w1.z, w1.w,
                            w2.x, w2.y, w2.z, w2.w};
#pragma unroll
            for (int r = 0; r < 4; ++r)
#pragma unroll
                for (int c = 0; c < 12; ++c) acc[r][c] += av[r] * wv[c];
        }
        __syncthreads();
    }

    // epilogue: h16 store + fused alpha
    float asr[12], adr[12];
#pragma unroll
    for (int c = 0; c < 12; ++c) {
        asr[c] = att_src[tx * 12 + c];
        adr[c] = att_dst[tx * 12 + c];
    }
#pragma unroll
    for (int r = 0; r < 4; ++r) {
        int rr = row0 + ty * 4 + r;
        bool ok = rr < rows;
        if (ok) {
            __half2* o = (__half2*)(out + (size_t)rr * 192 + tx * 12);
#pragma unroll
            for (int c = 0; c < 6; ++c)
                o[c] = __floats2half2_rn(acc[r][2 * c], acc[r][2 * c + 1]);
        }
        float s0 = 0, s1 = 0, s2 = 0, d0 = 0, d1 = 0, d2 = 0;
#pragma unroll
        for (int c = 0; c < 12; ++c) {
            int cc = tx * 12 + c;
            float p = acc[r][c] * asr[c];
            float q = acc[r][c] * adr[c];
            if (cc < 64)       { s0 += p; d0 += q; }
            else if (cc < 128) { s1 += p; d1 += q; }
            else               { s2 += p; d2 += q; }
        }
        for (int off = 1; off < 16; off <<= 1) {
            s0 += __shfl_xor(s0, off); s1 += __shfl_xor(s1, off); s2 += __shfl_xor(s2, off);
            d0 += __shfl_xor(d0, off); d1 += __shfl_xor(d1, off); d2 += __shfl_xor(d2, off);
        }
        if (tx == 0 && ok) {
            as4[rr * 4 + 0] = s0; as4[rr * 4 + 1] = s1; as4[rr * 4 + 2] = s2;
            ad4[rr * 4 + 0] = d0; ad4[rr * 4 + 1] = d1; ad4[rr * 4 + 2] = d2;
            float v0 = s0 + d0; v0 = v0 > 0.f ? v0 : NEG * v0;
            float v1 = s1 + d1; v1 = v1 > 0.f ? v1 : NEG * v1;
            float v2 = s2 + d2; v2 = v2 > 0.f ? v2 : NEG * v2;
            wself4[rr * 4 + 0] = __expf(v0);
            wself4[rr * 4 + 1] = __expf(v1);
            wself4[rr * 4 + 2] = __expf(v2);
        }
    }
}

// ---------------- aggregation: one wave per node, fp16 gathers, fully-predicated U=8 ----------------
// lane l (0..47): head hl=l>>4, channels (l&15)*4 .. +3 of that head
template <bool RELU>
__global__ __launch_bounds__(256) void aggregate_kernel(const __half* __restrict__ h,
                                                        const float* __restrict__ as_,
                                                        const float* __restrict__ ad4,
                                                        const float* __restrict__ wself4,
                                                        const float* __restrict__ bias,
                                                        const int* __restrict__ rowptr,
                                                        const int* __restrict__ col,
                                                        float* __restrict__ out, int n) {
    constexpr int U = 8;
    __shared__ float sh[4][192];
    int wid = (int)((blockIdx.x * blockDim.x + threadIdx.x) >> 6);
    int l = threadIdx.x & 63;
    int wv = threadIdx.x >> 6;
    bool valid = wid < n;
    int d = valid ? wid : 0;
    if (valid && l < 48) {
        int hl = l >> 4;
        int r0 = rowptr[d], r1 = rowptr[d + 1];
        float adh = ad4[d * 4 + hl];
        float w = wself4[d * 4 + hl];
        float2 sraw = *(const float2*)(h + (size_t)d * 192 + l * 4);
        float2 s01 = __half22float2(*(__half2*)&sraw.x);
        float2 s23 = __half22float2(*(__half2*)&sraw.y);
        float ax = w * s01.x, ay = w * s01.y, az = w * s23.x, aw = w * s23.y;
        float den = w;

        for (int j = r0; j < r1; j += U) {
            int s[U];
            bool act[U];
            float av[U];
            float2 g[U];
#pragma unroll
            for (int u = 0; u < U; ++u) {
                int jj = j + u;
                act[u] = jj < r1;
                s[u] = act[u] ? col[jj] : 0;
            }
#pragma unroll
            for (int u = 0; u < U; ++u) {
                float t = as_[s[u] * 4 + hl];
                av[u] = act[u] ? t : -1e30f;
            }
#pragma unroll
            for (int u = 0; u < U; ++u)
                g[u] = *(const float2*)(h + (size_t)s[u] * 192 + l * 4);
#pragma unroll
            for (int u = 0; u < U; ++u) {
                float v = av[u] + adh;
                v = v > 0.f ? v : NEG * v;
                float we = __expf(v);
                float2 g01 = __half22float2(*(__half2*)&g[u].x);
                float2 g23 = __half22float2(*(__half2*)&g[u].y);
                den += we;
                ax += we * g01.x;
                ay += we * g01.y;
                az += we * g23.x;
                aw += we * g23.y;
            }
        }
        float r = 1.f / den;
        float4 o = {ax * r, ay * r, az * r, aw * r};
        *(float4*)&sh[wv][l * 4] = o;
    }
    __syncthreads();
    if (valid) {
        float o = (sh[wv][l] + sh[wv][64 + l] + sh[wv][128 + l]) * (1.f / 3.f) + bias[l];
        if (RELU) o = fmaxf(o, 0.f);
        out[(size_t)d * 64 + l] = o;
    }
}

extern "C" void kernel_launch(void* const* d_in, const int* in_sizes, int n_in,
                              void* d_out, int out_size, void* d_ws, size_t ws_size,
                              hipStream_t stream) {
    const float* x = (const float*)d_in[0];       // [N,128]
    const int* ei = (const int*)d_in[1];          // [2,E]
    const float* W1 = (const float*)d_in[2];      // [128,192]
    const float* att_s1 = (const float*)d_in[3];  // [3,64] -> flat 192
    const float* att_d1 = (const float*)d_in[4];
    const float* b1 = (const float*)d_in[5];      // [64]
    const float* W2 = (const float*)d_in[6];      // [64,192]
    const float* att_s2 = (const float*)d_in[7];
    const float* att_d2 = (const float*)d_in[8];
    const float* b2 = (const float*)d_in[9];
    const int* src = ei;
    const int* dst = ei + N_EDGES;

    // workspace layout (16B-aligned blocks)
    __half* h16 = (__half*)d_ws;                         // N*192 halves
    float* as4 = (float*)(h16 + (size_t)N_NODES * 192);  // N*4
    float* ad4 = as4 + N_NODES * 4;                      // N*4
    float* wself4 = ad4 + N_NODES * 4;                   // N*4
    int* cnt = (int*)(wself4 + N_NODES * 4);             // N
    int* rowptr = cnt + N_NODES;                         // N+1
    int* col = rowptr + N_NODES + 1;                     // E
    int* partials = col + N_EDGES;                       // <=256

    float* outf = (float*)d_out;                         // doubles as layer-1 output [N,64]
    const int NB = (N_NODES + 255) / 256;

    // CSR build (shared by both layers)
    zero_kernel<<<(N_NODES + 255) / 256, 256, 0, stream>>>(cnt, N_NODES);
    count_kernel<<<(N_EDGES + 255) / 256, 256, 0, stream>>>(dst, cnt, N_EDGES);
    scan1_kernel<<<NB, 256, 0, stream>>>(cnt, rowptr, partials, N_NODES);
    scan2_kernel<<<1, 256, 0, stream>>>(partials, NB);
    scan3_kernel<<<NB, 256, 0, stream>>>(rowptr, partials, N_NODES);
    fill_kernel<<<(N_EDGES + 255) / 256, 256, 0, stream>>>(src, dst, rowptr, cnt, col, N_EDGES);

    // layer 1 (gemm + fused alpha)
    gemm_kernel<128><<<(N_NODES + 63) / 64, 256, 0, stream>>>(x, W1, h16, att_s1, att_d1,
                                                              as4, ad4, wself4, N_NODES);
    aggregate_kernel<true><<<(N_NODES + 3) / 4, 256, 0, stream>>>(h16, as4, ad4, wself4, b1,
                                                                  rowptr, col, outf, N_NODES);

    // layer 2 (reads layer-1 output from d_out, then overwrites d_out)
    gemm_kernel<64><<<(N_NODES + 63) / 64, 256, 0, stream>>>(outf, W2, h16, att_s2, att_d2,
                                                             as4, ad4, wself4, N_NODES);
    aggregate_kernel<false><<<(N_NODES + 3) / 4, 256, 0, stream>>>(h16, as4, ad4, wself4, b2,
                                                                   rowptr, col, outf, N_NODES);
}

// Round 8
// 363.756 us; speedup vs baseline: 1.4007x; 1.0011x over previous
//
#include <hip/hip_runtime.h>
#include <hip/hip_fp16.h>
#include <math.h>
#include <limits.h>

#define N_NODES 50000
#define N_EDGES 800000
#define NEG 0.2f

typedef _Float16 half8 __attribute__((ext_vector_type(8)));
typedef float floatx4 __attribute__((ext_vector_type(4)));

// ---------------- CSR build ----------------

__global__ void zero_kernel(int* a, int n) {
    int i = blockIdx.x * blockDim.x + threadIdx.x;
    if (i < n) a[i] = 0;
}

__global__ void count_kernel(const int* __restrict__ dst, int* cnt, int E) {
    int i = blockIdx.x * blockDim.x + threadIdx.x;
    if (i < E) atomicAdd(&cnt[dst[i]], 1);
}

__global__ void scan1_kernel(const int* __restrict__ cnt, int* rowptr, int* partials, int n) {
    __shared__ int sh[256];
    int tid = threadIdx.x;
    int i = blockIdx.x * 256 + tid;
    int v = (i < n) ? cnt[i] : 0;
    sh[tid] = v;
    __syncthreads();
    for (int off = 1; off < 256; off <<= 1) {
        int t = (tid >= off) ? sh[tid - off] : 0;
        __syncthreads();
        sh[tid] += t;
        __syncthreads();
    }
    if (i < n) rowptr[i] = sh[tid] - v;
    if (tid == 255) partials[blockIdx.x] = sh[255];
}

__global__ void scan2_kernel(int* partials, int nb) {
    __shared__ int sh[256];
    int tid = threadIdx.x;
    int v = (tid < nb) ? partials[tid] : 0;
    sh[tid] = v;
    __syncthreads();
    for (int off = 1; off < 256; off <<= 1) {
        int t = (tid >= off) ? sh[tid - off] : 0;
        __syncthreads();
        sh[tid] += t;
        __syncthreads();
    }
    if (tid < nb) partials[tid] = sh[tid] - v;
}

__global__ void scan3_kernel(int* rowptr, const int* __restrict__ partials, int n) {
    int i = blockIdx.x * blockDim.x + threadIdx.x;
    if (i < n) rowptr[i] += partials[i >> 8];
    if (i == 0) rowptr[n] = N_EDGES;
}

// atomic fill (order nondeterministic) + record original edge index for canonicalization
__global__ void fill_kernel(const int* __restrict__ src, const int* __restrict__ dst,
                            const int* __restrict__ rowptr, int* cnt, int* col, int* eidp, int E) {
    int i = blockIdx.x * blockDim.x + threadIdx.x;
    if (i < E) {
        int d = dst[i];
        int pos = rowptr[d] + atomicSub(&cnt[d], 1) - 1;
        col[pos] = src[i];
        eidp[pos] = i;
    }
}

// canonicalize: one wave per node, bitonic sort segment by original edge id.
// Result: col is a pure function of the input graph (bitwise deterministic).
__global__ void sortrow_kernel(const int* __restrict__ rowptr, int* col, int* eidp, int n) {
    int wid = (int)((blockIdx.x * blockDim.x + threadIdx.x) >> 6);
    int lane = threadIdx.x & 63;
    if (wid >= n) return;
    int r0 = rowptr[wid], r1 = rowptr[wid + 1];
    int deg = r1 - r0;
    if (deg <= 1) return;
    if (deg <= 64) {
        int key = (lane < deg) ? eidp[r0 + lane] : INT_MAX;
        int val = (lane < deg) ? col[r0 + lane] : 0;
#pragma unroll
        for (int k = 2; k <= 64; k <<= 1) {
#pragma unroll
            for (int j = k >> 1; j > 0; j >>= 1) {
                int pk = __shfl_xor(key, j);
                int pv = __shfl_xor(val, j);
                bool up = ((lane & k) == 0);
                bool lower = ((lane & j) == 0);
                bool take = lower ? ((pk < key) == up) : ((pk > key) == up);
                if (take) { key = pk; val = pv; }
            }
        }
        if (lane < deg) col[r0 + lane] = val;
    } else if (lane == 0) {
        // unreachable for Poisson(16) degrees; correct fallback anyway
        for (int i = r0 + 1; i < r1; ++i) {
            int ke = eidp[i], kv = col[i];
            int j = i - 1;
            while (j >= r0 && eidp[j] > ke) {
                eidp[j + 1] = eidp[j];
                col[j + 1] = col[j];
                --j;
            }
            eidp[j + 1] = ke;
            col[j + 1] = kv;
        }
    }
}

// ---------------- W[K][192] fp32 -> wt16[192][K] fp16 ----------------
template <int K>
__global__ void wtrans_kernel(const float* __restrict__ W, __half* __restrict__ wt) {
    int idx = blockIdx.x * blockDim.x + threadIdx.x;
    if (idx < 192 * K) {
        int n = idx / K, k = idx - n * K;
        wt[idx] = __float2half(W[k * 192 + n]);
    }
}

// ---------------- MFMA GEMM: A[rows][K] fp32 @ W[K][192] -> h16[rows][192]
// + fused alpha epilogue. Block: 256 thr = 4 waves x 16-row strips.
// A converted to fp16 in-register (same _rn rounding as a staging buffer).
template <int K>
__global__ __launch_bounds__(256) void mfma_gemm_kernel(const float* __restrict__ A,
                                                        const __half* __restrict__ wt,
                                                        __half* __restrict__ out,
                                                        const float* __restrict__ att_src,
                                                        const float* __restrict__ att_dst,
                                                        float* __restrict__ as4,
                                                        float* __restrict__ ad4,
                                                        float* __restrict__ wself4, int rows) {
    constexpr int KP = K + 8;
    __shared__ __align__(16) __half lds[192 * KP];  // wt tile; later reused for output staging
    int tid = threadIdx.x;
    int lane = tid & 63;
    int wv = tid >> 6;
    int ln = lane & 15;
    int q = lane >> 4;

    // stage wt -> LDS [n][KP]
    for (int idx = tid; idx < 192 * (K / 8); idx += 256) {
        int n = idx / (K / 8), kk = (idx % (K / 8)) * 8;
        *(float4*)(lds + n * KP + kk) = *(const float4*)(wt + n * K + kk);
    }

    // A fragments: lane ln -> row m0+ln, quad q -> k offset q*8 (fp32 load, cvt)
    int m0 = blockIdx.x * 64 + wv * 16;
    int m = m0 + ln;
    int mc = m < rows ? m : 0;
    half8 afr[K / 32];
#pragma unroll
    for (int kt = 0; kt < K / 32; ++kt) {
        float4 a0 = *(const float4*)(A + (size_t)mc * K + kt * 32 + q * 8);
        float4 a1 = *(const float4*)(A + (size_t)mc * K + kt * 32 + q * 8 + 4);
        half8 f;
        f[0] = (_Float16)a0.x; f[1] = (_Float16)a0.y; f[2] = (_Float16)a0.z; f[3] = (_Float16)a0.w;
        f[4] = (_Float16)a1.x; f[5] = (_Float16)a1.y; f[6] = (_Float16)a1.z; f[7] = (_Float16)a1.w;
        afr[kt] = f;
    }

    __syncthreads();

    floatx4 acc[12];
#pragma unroll
    for (int c = 0; c < 12; ++c) acc[c] = (floatx4){0.f, 0.f, 0.f, 0.f};

#pragma unroll
    for (int kt = 0; kt < K / 32; ++kt) {
#pragma unroll
        for (int c = 0; c < 12; ++c) {
            half8 b = *(const half8*)(lds + (c * 16 + ln) * KP + kt * 32 + q * 8);
            acc[c] = __builtin_amdgcn_mfma_f32_16x16x32_f16(afr[kt], b, acc[c], 0, 0, 0);
        }
    }

    // fused alpha epilogue: lane holds C rows m0+q*4+r, col c*16+ln
    float asv[12], adv[12];
#pragma unroll
    for (int c = 0; c < 12; ++c) {
        asv[c] = att_src[c * 16 + ln];
        adv[c] = att_dst[c * 16 + ln];
    }
#pragma unroll
    for (int r = 0; r < 4; ++r) {
        float s0 = 0, s1 = 0, s2 = 0, d0 = 0, d1 = 0, d2 = 0;
#pragma unroll
        for (int c = 0; c < 4; ++c) { s0 += acc[c][r] * asv[c]; d0 += acc[c][r] * adv[c]; }
#pragma unroll
        for (int c = 4; c < 8; ++c) { s1 += acc[c][r] * asv[c]; d1 += acc[c][r] * adv[c]; }
#pragma unroll
        for (int c = 8; c < 12; ++c) { s2 += acc[c][r] * asv[c]; d2 += acc[c][r] * adv[c]; }
        for (int off = 1; off < 16; off <<= 1) {
            s0 += __shfl_xor(s0, off); s1 += __shfl_xor(s1, off); s2 += __shfl_xor(s2, off);
            d0 += __shfl_xor(d0, off); d1 += __shfl_xor(d1, off); d2 += __shfl_xor(d2, off);
        }
        int row = m0 + q * 4 + r;
        if (ln == 0 && row < rows) {
            as4[row * 4 + 0] = s0; as4[row * 4 + 1] = s1; as4[row * 4 + 2] = s2;
            ad4[row * 4 + 0] = d0; ad4[row * 4 + 1] = d1; ad4[row * 4 + 2] = d2;
            float v0 = s0 + d0; v0 = v0 > 0.f ? v0 : NEG * v0;
            float v1 = s1 + d1; v1 = v1 > 0.f ? v1 : NEG * v1;
            float v2 = s2 + d2; v2 = v2 > 0.f ? v2 : NEG * v2;
            wself4[row * 4 + 0] = __expf(v0);
            wself4[row * 4 + 1] = __expf(v1);
            wself4[row * 4 + 2] = __expf(v2);
        }
    }

    // h16 store via LDS for coalescing
    __syncthreads();
#pragma unroll
    for (int c = 0; c < 12; ++c)
#pragma unroll
        for (int r = 0; r < 4; ++r)
            lds[(wv * 16 + q * 4 + r) * 192 + c * 16 + ln] = __float2half(acc[c][r]);
    __syncthreads();
    int row0 = blockIdx.x * 64;
    for (int idx = tid; idx < 1536; idx += 256) {
        int row = (idx * 8) / 192, off = (idx * 8) % 192;
        if (row0 + row < rows)
            *(float4*)(out + (size_t)(row0 + row) * 192 + off) = *(float4*)(lds + row * 192 + off);
    }
}

// ---------------- aggregation: one wave per node, fp16 gathers, fully-predicated U=8 ----------------
template <bool RELU>
__global__ __launch_bounds__(256) void aggregate_kernel(const __half* __restrict__ h,
                                                        const float* __restrict__ as_,
                                                        const float* __restrict__ ad4,
                                                        const float* __restrict__ wself4,
                                                        const float* __restrict__ bias,
                                                        const int* __restrict__ rowptr,
                                                        const int* __restrict__ col,
                                                        float* __restrict__ out, int n) {
    constexpr int U = 8;
    __shared__ float sh[4][192];
    int wid = (int)((blockIdx.x * blockDim.x + threadIdx.x) >> 6);
    int l = threadIdx.x & 63;
    int wv = threadIdx.x >> 6;
    bool valid = wid < n;
    int d = valid ? wid : 0;
    if (valid && l < 48) {
        int hl = l >> 4;
        int r0 = rowptr[d], r1 = rowptr[d + 1];
        float adh = ad4[d * 4 + hl];
        float w = wself4[d * 4 + hl];
        float2 sraw = *(const float2*)(h + (size_t)d * 192 + l * 4);
        float2 s01 = __half22float2(*(__half2*)&sraw.x);
        float2 s23 = __half22float2(*(__half2*)&sraw.y);
        float ax = w * s01.x, ay = w * s01.y, az = w * s23.x, aw = w * s23.y;
        float den = w;

        for (int j = r0; j < r1; j += U) {
            int s[U];
            bool act[U];
            float av[U];
            float2 g[U];
#pragma unroll
            for (int u = 0; u < U; ++u) {
                int jj = j + u;
                act[u] = jj < r1;
                s[u] = act[u] ? col[jj] : 0;
            }
#pragma unroll
            for (int u = 0; u < U; ++u) {
                float t = as_[s[u] * 4 + hl];
                av[u] = act[u] ? t : -1e30f;
            }
#pragma unroll
            for (int u = 0; u < U; ++u)
                g[u] = *(const float2*)(h + (size_t)s[u] * 192 + l * 4);
#pragma unroll
            for (int u = 0; u < U; ++u) {
                float v = av[u] + adh;
                v = v > 0.f ? v : NEG * v;
                float we = __expf(v);
                float2 g01 = __half22float2(*(__half2*)&g[u].x);
                float2 g23 = __half22float2(*(__half2*)&g[u].y);
                den += we;
                ax += we * g01.x;
                ay += we * g01.y;
                az += we * g23.x;
                aw += we * g23.y;
            }
        }
        float r = 1.f / den;
        float4 o = {ax * r, ay * r, az * r, aw * r};
        *(float4*)&sh[wv][l * 4] = o;
    }
    __syncthreads();
    if (valid) {
        float o = (sh[wv][l] + sh[wv][64 + l] + sh[wv][128 + l]) * (1.f / 3.f) + bias[l];
        if (RELU) o = fmaxf(o, 0.f);
        out[(size_t)d * 64 + l] = o;
    }
}

extern "C" void kernel_launch(void* const* d_in, const int* in_sizes, int n_in,
                              void* d_out, int out_size, void* d_ws, size_t ws_size,
                              hipStream_t stream) {
    const float* x = (const float*)d_in[0];       // [N,128]
    const int* ei = (const int*)d_in[1];          // [2,E]
    const float* W1 = (const float*)d_in[2];      // [128,192]
    const float* att_s1 = (const float*)d_in[3];  // [3,64] flat 192
    const float* att_d1 = (const float*)d_in[4];
    const float* b1 = (const float*)d_in[5];      // [64]
    const float* W2 = (const float*)d_in[6];      // [64,192]
    const float* att_s2 = (const float*)d_in[7];
    const float* att_d2 = (const float*)d_in[8];
    const float* b2 = (const float*)d_in[9];
    const int* src = ei;
    const int* dst = ei + N_EDGES;

    // workspace layout (16B-aligned blocks)
    __half* h16 = (__half*)d_ws;                           // N*192
    __half* wt1 = h16 + (size_t)N_NODES * 192;             // 192*128
    __half* wt2 = wt1 + 192 * 128;                         // 192*64
    float* as4 = (float*)(wt2 + 192 * 64);                 // N*4
    float* ad4 = as4 + N_NODES * 4;                        // N*4
    float* wself4 = ad4 + N_NODES * 4;                     // N*4
    int* cnt = (int*)(wself4 + N_NODES * 4);               // N
    int* rowptr = cnt + N_NODES;                           // N+1
    int* col = rowptr + N_NODES + 1;                       // E
    int* eidp = col + N_EDGES;                             // E
    int* partials = eidp + N_EDGES;                        // <=256

    float* outf = (float*)d_out;                           // layer-1 output [N,64] too
    const int NB = (N_NODES + 255) / 256;

    // weight transposes (independent of CSR)
    wtrans_kernel<128><<<(192 * 128 + 255) / 256, 256, 0, stream>>>(W1, wt1);
    wtrans_kernel<64><<<(192 * 64 + 255) / 256, 256, 0, stream>>>(W2, wt2);

    // CSR build (shared by both layers), canonicalized for determinism
    zero_kernel<<<(N_NODES + 255) / 256, 256, 0, stream>>>(cnt, N_NODES);
    count_kernel<<<(N_EDGES + 255) / 256, 256, 0, stream>>>(dst, cnt, N_EDGES);
    scan1_kernel<<<NB, 256, 0, stream>>>(cnt, rowptr, partials, N_NODES);
    scan2_kernel<<<1, 256, 0, stream>>>(partials, NB);
    scan3_kernel<<<NB, 256, 0, stream>>>(rowptr, partials, N_NODES);
    fill_kernel<<<(N_EDGES + 255) / 256, 256, 0, stream>>>(src, dst, rowptr, cnt, col, eidp, N_EDGES);
    sortrow_kernel<<<(N_NODES + 3) / 4, 256, 0, stream>>>(rowptr, col, eidp, N_NODES);

    // layer 1
    mfma_gemm_kernel<128><<<(N_NODES + 63) / 64, 256, 0, stream>>>(x, wt1, h16, att_s1, att_d1,
                                                                   as4, ad4, wself4, N_NODES);
    aggregate_kernel<true><<<(N_NODES + 3) / 4, 256, 0, stream>>>(h16, as4, ad4, wself4, b1,
                                                                  rowptr, col, outf, N_NODES);

    // layer 2
    mfma_gemm_kernel<64><<<(N_NODES + 63) / 64, 256, 0, stream>>>(outf, wt2, h16, att_s2, att_d2,
                                                                  as4, ad4, wself4, N_NODES);
    aggregate_kernel<false><<<(N_NODES + 3) / 4, 256, 0, stream>>>(h16, as4, ad4, wself4, b2,
                                                                   rowptr, col, outf, N_NODES);
}